// Round 10
// baseline (5757.390 us; speedup 1.0000x reference)
//
#include <hip/hip_runtime.h>

// ---------------------------------------------------------------------------
// BiGRU encoder, MI355X. Round 10 = round 9 with ONE instruction-level change:
// h is published via no-return global_atomic_swap_x2 instead of write-through
// stores. Memory-side atomics execute at the L3 coherence point and leave the
// line L3-resident -> consumers' cold loads fill from L3 (~450cy) not HBM
// (~900cy). FETCH_SIZE is the tell-tale: 526 MB (=8 XCD x full re-read from
// HBM) should collapse to <200 MB if the hypothesis is right.
//
// 64 blocks, 128 threads (2 waves), 1 block/CU.
//   wave A: gh = h@Whh^T (48 MFMA, B from AGPR) + gates + h publish (atomics).
//   wave B: gi = x@Wih^T + residual -> LDS FIFO (RD=4 ahead) + out[] stores.
//
// ws layout:
//   Xb   [T][B][F] bf16      33,554,432 B
//   Hf   [T][B][F] bf16      33,554,432 B
//   Hb   [T][B][F] bf16      33,554,432 B
//   Wb   [2][2][1536][512]    6,291,456 B   (dir, src{0=Whh,1=Wih})
//   flags 2 dirs x 4 replicas x 32 int
// ---------------------------------------------------------------------------

#define TT 2048
#define BB 16
#define FF 512
#define LL 10
#define RD 4
#define NTHR 128

typedef __attribute__((ext_vector_type(8))) short short8;
typedef __attribute__((ext_vector_type(4))) int   int4v;
typedef __attribute__((ext_vector_type(2))) int   int2v;
typedef __attribute__((ext_vector_type(4))) float f32x4;

// D = A*B + C, B operand pinned to AGPR (weights live there loop-invariantly).
#define MFMA_AB(acc, a, b) \
  asm("v_mfma_f32_16x16x32_bf16 %0, %1, %2, %0" : "+v"(acc) : "v"(a), "a"(b))

__device__ __forceinline__ unsigned short f2bf(float f) {
  union { float f; unsigned int u; } v; v.f = f;
  unsigned int u = v.u;
  return (unsigned short)((u + 0x7fffu + ((u >> 16) & 1u)) >> 16);
}
__device__ __forceinline__ float bf2f(unsigned short h) {
  union { unsigned int u; float f; } v; v.u = ((unsigned int)h) << 16;
  return v.f;
}

__global__ void prep_x(const float* __restrict__ x, unsigned short* __restrict__ Xb) {
  int i = blockIdx.x * blockDim.x + threadIdx.x;
  int f = i & (FF - 1);
  int b = (i >> 9) & (BB - 1);
  int t = i >> 13;
  Xb[i] = f2bf(x[(size_t)b * (TT * 1025) + t * 1025 + f]);
}

__global__ void prep_w(const float* __restrict__ a, const float* __restrict__ b,
                       const float* __restrict__ c, const float* __restrict__ d,
                       unsigned short* __restrict__ Wb) {
  const int M = 1536 * 512;
  int i = blockIdx.x * blockDim.x + threadIdx.x;
  int m = i / M, r = i - m * M;
  const float* src = (m == 0) ? a : (m == 1) ? b : (m == 2) ? c : d;
  Wb[i] = f2bf(src[r]);
}

__global__ void prep_flags(int* __restrict__ flags) {
  int i = threadIdx.x;
  if (i < 256) flags[i] = 0;
}

// ---------------------------------------------------------------------------
__global__ void __launch_bounds__(NTHR, 1) bigru_rec(
    const unsigned short* __restrict__ Xb,
    unsigned short* __restrict__ Hf, unsigned short* __restrict__ Hb,
    const unsigned short* __restrict__ Wb,
    const float* __restrict__ bih_f, const float* __restrict__ bhh_f,
    const float* __restrict__ bih_b, const float* __restrict__ bhh_b,
    int* __restrict__ flags, float* __restrict__ out)
{
  const int bid  = blockIdx.x;
  const int d    = bid >> 5;           // direction
  const int j    = bid & 31;           // slice (16 hidden cols)
  const int tid  = threadIdx.x;
  const int w    = tid >> 6;           // 0 = gh wave, 1 = gi wave
  const int lane = tid & 63;
  const int l15  = lane & 15;
  const int hi   = lane >> 4;
  const int lk   = hi * 8;
  const int col  = j * 16 + l15;

  unsigned short* Hst = d ? Hb : Hf;
  int* flg = flags + d * 128;          // 4 replica lines of 32 ints
  const float* bih = d ? bih_b : bih_f;
  const float* bhh = d ? bhh_b : bhh_f;

  __shared__ float fifo[RD][64][17];   // B -> A : gi gates + residual x
  __shared__ float fout[RD][64][5];    // A -> B : h2 values for out[] stores
  __shared__ int wrote_s, consumed_s, outA_s, outdone_s;
  if (tid == 0) { wrote_s = 0; consumed_s = 0; outA_s = 0; outdone_s = 0; }
  __syncthreads();

  // Weights: plain loads; used only via "a" MFMA constraint -> homed in AGPRs.
  const int src = w;                   // 0=Whh, 1=Wih
  int4v wf[3][16];
#pragma unroll
  for (int g = 0; g < 3; ++g) {
    const unsigned short* wrow =
        Wb + (size_t)((d * 2 + src) * 1536 + g * 512 + j * 16 + l15) * 512 + lk;
#pragma unroll
    for (int kk = 0; kk < 16; ++kk)
      wf[g][kk] = *(const int4v*)(wrow + kk * 32);
  }

  if (w == 0) {
    // ====================== WAVE A: gh + gates + publish ===================
    __builtin_amdgcn_s_setprio(1);
    const float bh0 = bhh[col], bh1 = bhh[512 + col], bh2 = bhh[1024 + col];
    float hc[4] = {0.f, 0.f, 0.f, 0.f};
    int* myrep = flg + (j & 3) * 32;   // this consumer's flag replica line

    for (int t = 0; t < TT; ++t) {
      f32x4 a0 = {0,0,0,0}, a1 = {0,0,0,0}, a2 = {0,0,0,0},
            a3 = {0,0,0,0}, a4 = {0,0,0,0}, a5 = {0,0,0,0};
      if (t > 0) {
        int vv = t;
        bool first = true;
        for (;;) {
          if (lane < 32)
            vv = __hip_atomic_load(myrep + lane, __ATOMIC_RELAXED,
                                   __HIP_MEMORY_SCOPE_AGENT);
          if (__all(lane < 32 ? (vv >= t) : 1)) break;
          if (!first) asm volatile("s_sleep 1");   // backoff the poll storm
          first = false;
        }
        __builtin_amdgcn_sched_barrier(0);   // no load hoisting above the poll
        const unsigned short* Arow =
            Hst + (size_t)((t - 1) * BB + l15) * FF + lk;
        int4v af[16];
#pragma unroll
        for (int kk = 0; kk < 16; ++kk)
          af[kk] = *(const int4v*)(Arow + kk * 32);
#pragma unroll
        for (int kk = 0; kk < 16; kk += 2) {
          MFMA_AB(a0, af[kk],     wf[0][kk]);
          MFMA_AB(a2, af[kk],     wf[1][kk]);
          MFMA_AB(a4, af[kk],     wf[2][kk]);
          MFMA_AB(a1, af[kk + 1], wf[0][kk + 1]);
          MFMA_AB(a3, af[kk + 1], wf[1][kk + 1]);
          MFMA_AB(a5, af[kk + 1], wf[2][kk + 1]);
        }
        asm volatile("s_nop 7\n\ts_nop 7");  // MFMA D -> VALU hazard guard
      }
      const int slot = t & (RD - 1);
      while (__hip_atomic_load(&wrote_s, __ATOMIC_ACQUIRE,
                               __HIP_MEMORY_SCOPE_WORKGROUP) < t + 1) {}
      float fr[4], fz[4], fn[4], fx[4];
#pragma unroll
      for (int jj = 0; jj < 4; ++jj) {
        fr[jj] = fifo[slot][lane][jj];
        fz[jj] = fifo[slot][lane][4 + jj];
        fn[jj] = fifo[slot][lane][8 + jj];
        fx[jj] = fifo[slot][lane][12 + jj];
      }
      __hip_atomic_store(&consumed_s, t + 1, __ATOMIC_RELEASE,
                         __HIP_MEMORY_SCOPE_WORKGROUP);

      unsigned short us[4]; float h2v[4];
#pragma unroll
      for (int jj = 0; jj < 4; ++jj) {
        const float ghr = a0[jj] + a1[jj] + bh0;
        const float ghz = a2[jj] + a3[jj] + bh1;
        const float ghn = a4[jj] + a5[jj] + bh2;
        const float rr = 1.f / (1.f + __expf(-(fr[jj] + ghr)));
        const float zz = 1.f / (1.f + __expf(-(fz[jj] + ghz)));
        const float ee = __expf(2.f * (fn[jj] + rr * ghn));
        const float nn = 1.f - 2.f / (ee + 1.f);        // tanh, inf-safe
        const float h2 = (1.f - zz) * nn + zz * hc[jj] + fx[jj];
        hc[jj] = h2; h2v[jj] = h2; us[jj] = f2bf(h2);
      }
      // hand h2 to wave B for the out[] stores (keeps A's vmcnt queue clean)
      while (__hip_atomic_load(&outdone_s, __ATOMIC_ACQUIRE,
                               __HIP_MEMORY_SCOPE_WORKGROUP) <= t - RD) {}
#pragma unroll
      for (int jj = 0; jj < 4; ++jj)
        fout[slot][lane][jj] = h2v[jj];
      __hip_atomic_store(&outA_s, t + 1, __ATOMIC_RELEASE,
                         __HIP_MEMORY_SCOPE_WORKGROUP);

      // --- h publish: shfl-transpose 512B into 32 lanes x 16B ---
      unsigned int word4[4];
#pragma unroll
      for (int jj = 0; jj < 4; ++jj) {
        const unsigned int other =
            (unsigned int)(unsigned short)__shfl_xor((int)us[jj], 1);
        word4[jj] = (unsigned int)us[jj] | (other << 16);  // valid in even lanes
      }
      const int s  = lane & 31;        // writer slot
      const int rs = s >> 1;           // row 0..15
      const int hs = s & 1;            // col-half (8 cols = 16B)
      int4v pk;
#pragma unroll
      for (int k = 0; k < 4; ++k) {
        const int srcl = ((rs >> 2) << 4) + hs * 8 + 2 * k;  // even lane
        unsigned int v = 0;
#pragma unroll
        for (int jj = 0; jj < 4; ++jj) {
          const unsigned int tmp = (unsigned int)__shfl((int)word4[jj], srcl);
          if ((rs & 3) == jj) v = tmp;
        }
        pk[k] = (int)v;
      }
      if (lane < 32) {
        unsigned short* wp = Hst + (size_t)(t * BB + rs) * FF + j * 16 + hs * 8;
        // memory-side atomics: line stays L3-resident for the 31 consumers
        const int2v d0 = {pk[0], pk[1]};
        const int2v d1 = {pk[2], pk[3]};
        asm volatile("global_atomic_swap_x2 %0, %1, off"
                     :: "v"(wp), "v"(d0) : "memory");
        asm volatile("global_atomic_swap_x2 %0, %1, off offset:8"
                     :: "v"(wp), "v"(d1) : "memory");
      }
      asm volatile("s_waitcnt vmcnt(0)" ::: "memory");   // h at coherence point
      if (lane == 0) {                 // publish to all 4 replica lines
#pragma unroll
        for (int r = 0; r < 4; ++r)
          __hip_atomic_store(flg + r * 32 + j, t + 1, __ATOMIC_RELAXED,
                             __HIP_MEMORY_SCOPE_AGENT);
      }
    }
  } else {
    // ============ WAVE B: gi + residual -> FIFO, and out[] stores ==========
    const float bi0 = bih[col], bi1 = bih[512 + col], bi2 = bih[1024 + col];
    int odone = 0;                     // local mirror of outdone_s

    // drain available h2 slots -> out[] (called from spins + each iteration)
    auto drain_out = [&]() {
      int avail = __hip_atomic_load(&outA_s, __ATOMIC_ACQUIRE,
                                    __HIP_MEMORY_SCOPE_WORKGROUP);
      while (odone < avail) {
        const int o = odone & (RD - 1);
        if (odone >= LL && odone < TT - LL) {
#pragma unroll
          for (int jj = 0; jj < 4; ++jj) {
            const float hv = fout[o][lane][jj];
            out[((size_t)(hi * 4 + jj) * (TT - 2 * LL) + (odone - LL)) * 1024
                + d * 512 + col] = hv;
          }
        } else {
#pragma unroll
          for (int jj = 0; jj < 4; ++jj) (void)fout[o][lane][jj];
        }
        ++odone;
        __hip_atomic_store(&outdone_s, odone, __ATOMIC_RELEASE,
                           __HIP_MEMORY_SCOPE_WORKGROUP);
      }
    };

    for (int t = 0; t < TT; ++t) {
      const int slot = t & (RD - 1);
      while (t - __hip_atomic_load(&consumed_s, __ATOMIC_ACQUIRE,
                                   __HIP_MEMORY_SCOPE_WORKGROUP) >= RD) {
        drain_out();
      }
      const int tx = d ? (TT - 1 - t) : t;
      const unsigned short* Arow = Xb + (size_t)(tx * BB + l15) * FF + lk;
      int4v af[16];
#pragma unroll
      for (int kk = 0; kk < 16; ++kk)
        af[kk] = *(const int4v*)(Arow + kk * 32);
      f32x4 a0 = {0,0,0,0}, a1 = {0,0,0,0}, a2 = {0,0,0,0},
            a3 = {0,0,0,0}, a4 = {0,0,0,0}, a5 = {0,0,0,0};
#pragma unroll
      for (int kk = 0; kk < 16; kk += 2) {
        MFMA_AB(a0, af[kk],     wf[0][kk]);
        MFMA_AB(a2, af[kk],     wf[1][kk]);
        MFMA_AB(a4, af[kk],     wf[2][kk]);
        MFMA_AB(a1, af[kk + 1], wf[0][kk + 1]);
        MFMA_AB(a3, af[kk + 1], wf[1][kk + 1]);
        MFMA_AB(a5, af[kk + 1], wf[2][kk + 1]);
      }
      asm volatile("s_nop 7\n\ts_nop 7");
      float xv[4];
#pragma unroll
      for (int jj = 0; jj < 4; ++jj)
        xv[jj] = bf2f(Xb[(size_t)(tx * BB + hi * 4 + jj) * FF + col]);
#pragma unroll
      for (int jj = 0; jj < 4; ++jj) {
        fifo[slot][lane][jj]      = a0[jj] + a1[jj] + bi0;
        fifo[slot][lane][4 + jj]  = a2[jj] + a3[jj] + bi1;
        fifo[slot][lane][8 + jj]  = a4[jj] + a5[jj] + bi2;
        fifo[slot][lane][12 + jj] = xv[jj];
      }
      __hip_atomic_store(&wrote_s, t + 1, __ATOMIC_RELEASE,
                         __HIP_MEMORY_SCOPE_WORKGROUP);
      drain_out();
    }
    while (odone < TT) drain_out();     // tail: finish remaining out[] stores
  }
}

// ---------------------------------------------------------------------------
extern "C" void kernel_launch(void* const* d_in, const int* in_sizes, int n_in,
                              void* d_out, int out_size, void* d_ws, size_t ws_size,
                              hipStream_t stream) {
  const float* x     = (const float*)d_in[0];
  const float* Wih_f = (const float*)d_in[1];
  const float* Whh_f = (const float*)d_in[2];
  const float* bih_f = (const float*)d_in[3];
  const float* bhh_f = (const float*)d_in[4];
  const float* Wih_b = (const float*)d_in[5];
  const float* Whh_b = (const float*)d_in[6];
  const float* bih_b = (const float*)d_in[7];
  const float* bhh_b = (const float*)d_in[8];
  float* out = (float*)d_out;

  char* ws = (char*)d_ws;
  unsigned short* Xb = (unsigned short*)ws;
  unsigned short* Hf = (unsigned short*)(ws + (size_t)33554432);
  unsigned short* Hb = (unsigned short*)(ws + (size_t)2 * 33554432);
  unsigned short* Wb = (unsigned short*)(ws + (size_t)3 * 33554432);
  int* flags         = (int*)(ws + (size_t)3 * 33554432 + 6291456);

  prep_x<<<65536, 256, 0, stream>>>(x, Xb);
  prep_w<<<12288, 256, 0, stream>>>(Whh_f, Wih_f, Whh_b, Wih_b, Wb);
  prep_flags<<<1, 256, 0, stream>>>(flags);
  bigru_rec<<<64, NTHR, 0, stream>>>(Xb, Hf, Hb, Wb, bih_f, bhh_f, bih_b, bhh_b,
                                     flags, out);
}

// Round 11
// 5533.870 us; speedup vs baseline: 1.0404x; 1.0404x over previous
//
#include <hip/hip_runtime.h>

// ---------------------------------------------------------------------------
// BiGRU encoder, MI355X. Round 11 = round 8 base with SWAPPED MFMA operands:
// D = Whh(A, AGPR) x h(B) gives lane = batch row, regs = 4 ADJACENT out-cols.
//  - h publish: 2 in-lane packs + 1 shfl_xor(16) (was 20 bpermutes)
//  - out[]: one dwordx4/lane (was 4 scattered dwords)
//  - xv: one 8B load (was 4 scalar); biases: float4/gate
// Also: no s_sleep backoff (poll RTT self-paces), no r9 fout relay, r8 sc0sc1
// write-through h stores (r10 atomics reverted).
//
// 64 blocks, 128 threads (2 waves), 1 block/CU.
//   wave A: gh = Whh x h (48 MFMA, A from AGPR) + gates + publish + out[].
//   wave B: gi = Wih x x + residual -> LDS FIFO (runs ahead, RD=4).
//
// ws layout:
//   Xb   [T][B][F] bf16      33,554,432 B
//   Hf   [T][B][F] bf16      33,554,432 B
//   Hb   [T][B][F] bf16      33,554,432 B
//   Wb   [2][2][1536][512]    6,291,456 B   (dir, src{0=Whh,1=Wih})
//   flags 2 dirs x 4 replicas x 32 int
// ---------------------------------------------------------------------------

#define TT 2048
#define BB 16
#define FF 512
#define LL 10
#define RD 4
#define NTHR 128

typedef __attribute__((ext_vector_type(8))) short short8;
typedef __attribute__((ext_vector_type(4))) int   int4v;
typedef __attribute__((ext_vector_type(2))) int   int2v;
typedef __attribute__((ext_vector_type(4))) float f32x4;

// D = A*B + C with A (weights) pinned to AGPR, B (activations) in VGPR.
#define MFMA_WA(acc, wfa, afb) \
  asm("v_mfma_f32_16x16x32_bf16 %0, %1, %2, %0" : "+v"(acc) : "a"(wfa), "v"(afb))

__device__ __forceinline__ unsigned short f2bf(float f) {
  union { float f; unsigned int u; } v; v.f = f;
  unsigned int u = v.u;
  return (unsigned short)((u + 0x7fffu + ((u >> 16) & 1u)) >> 16);
}
__device__ __forceinline__ float bf2f(unsigned short h) {
  union { unsigned int u; float f; } v; v.u = ((unsigned int)h) << 16;
  return v.f;
}

__global__ void prep_x(const float* __restrict__ x, unsigned short* __restrict__ Xb) {
  int i = blockIdx.x * blockDim.x + threadIdx.x;
  int f = i & (FF - 1);
  int b = (i >> 9) & (BB - 1);
  int t = i >> 13;
  Xb[i] = f2bf(x[(size_t)b * (TT * 1025) + t * 1025 + f]);
}

__global__ void prep_w(const float* __restrict__ a, const float* __restrict__ b,
                       const float* __restrict__ c, const float* __restrict__ d,
                       unsigned short* __restrict__ Wb) {
  const int M = 1536 * 512;
  int i = blockIdx.x * blockDim.x + threadIdx.x;
  int m = i / M, r = i - m * M;
  const float* src = (m == 0) ? a : (m == 1) ? b : (m == 2) ? c : d;
  Wb[i] = f2bf(src[r]);
}

__global__ void prep_flags(int* __restrict__ flags) {
  int i = threadIdx.x;
  if (i < 256) flags[i] = 0;
}

// ---------------------------------------------------------------------------
__global__ void __launch_bounds__(NTHR, 1) bigru_rec(
    const unsigned short* __restrict__ Xb,
    unsigned short* __restrict__ Hf, unsigned short* __restrict__ Hb,
    const unsigned short* __restrict__ Wb,
    const float* __restrict__ bih_f, const float* __restrict__ bhh_f,
    const float* __restrict__ bih_b, const float* __restrict__ bhh_b,
    int* __restrict__ flags, float* __restrict__ out)
{
  const int bid  = blockIdx.x;
  const int d    = bid >> 5;           // direction
  const int j    = bid & 31;           // slice (16 hidden cols)
  const int tid  = threadIdx.x;
  const int w    = tid >> 6;           // 0 = gh wave, 1 = gi wave
  const int lane = tid & 63;
  const int l15  = lane & 15;          // batch row (D col after swap)
  const int hi   = lane >> 4;          // col-block quarter (D rows hi*4+jj)
  const int lk   = hi * 8;
  const int cb   = j * 16 + hi * 4;    // this lane's first out-col

  unsigned short* Hst = d ? Hb : Hf;
  int* flg = flags + d * 128;          // 4 replica lines of 32 ints
  const float* bih = d ? bih_b : bih_f;
  const float* bhh = d ? bhh_b : bhh_f;

  __shared__ float fifo[RD][64][17];   // B -> A : gi gates + residual x
  __shared__ int wrote_s, consumed_s;
  if (tid == 0) { wrote_s = 0; consumed_s = 0; }
  __syncthreads();

  // Weights: plain loads; used only via "a" MFMA constraint -> homed in AGPRs.
  // A-operand layout: lane&15 = A row = out-col (W row), K = (lane>>4)*8.
  const int src = w;                   // 0=Whh, 1=Wih
  int4v wf[3][16];
#pragma unroll
  for (int g = 0; g < 3; ++g) {
    const unsigned short* wrow =
        Wb + (size_t)((d * 2 + src) * 1536 + g * 512 + j * 16 + l15) * 512 + lk;
#pragma unroll
    for (int kk = 0; kk < 16; ++kk)
      wf[g][kk] = *(const int4v*)(wrow + kk * 32);
  }

  if (w == 0) {
    // ====================== WAVE A: gh + gates + publish ===================
    __builtin_amdgcn_s_setprio(1);
    // 4 adjacent-col biases per lane
    const f32x4 bh0 = *(const f32x4*)(bhh + cb);
    const f32x4 bh1 = *(const f32x4*)(bhh + 512 + cb);
    const f32x4 bh2 = *(const f32x4*)(bhh + 1024 + cb);
    float hc[4] = {0.f, 0.f, 0.f, 0.f};   // carry: batch l15, cols cb+jj
    int* myrep = flg + (j & 3) * 32;   // this consumer's flag replica line

    for (int t = 0; t < TT; ++t) {
      f32x4 a0 = {0,0,0,0}, a1 = {0,0,0,0}, a2 = {0,0,0,0},
            a3 = {0,0,0,0}, a4 = {0,0,0,0}, a5 = {0,0,0,0};
      if (t > 0) {
        int vv = t;
        for (;;) {
          if (lane < 32)
            vv = __hip_atomic_load(myrep + lane, __ATOMIC_RELAXED,
                                   __HIP_MEMORY_SCOPE_AGENT);
          if (__all(lane < 32 ? (vv >= t) : 1)) break;
        }
        __builtin_amdgcn_sched_barrier(0);   // no load hoisting above the poll
        // B-operand (h rows): lane&15 = batch row, K = (lane>>4)*8 -> same
        // addressing as before the swap.
        const unsigned short* Arow =
            Hst + (size_t)((t - 1) * BB + l15) * FF + lk;
        int4v af[16];
#pragma unroll
        for (int kk = 0; kk < 16; ++kk)
          af[kk] = *(const int4v*)(Arow + kk * 32);
#pragma unroll
        for (int kk = 0; kk < 16; kk += 2) {
          MFMA_WA(a0, wf[0][kk],     af[kk]);
          MFMA_WA(a2, wf[1][kk],     af[kk]);
          MFMA_WA(a4, wf[2][kk],     af[kk]);
          MFMA_WA(a1, wf[0][kk + 1], af[kk + 1]);
          MFMA_WA(a3, wf[1][kk + 1], af[kk + 1]);
          MFMA_WA(a5, wf[2][kk + 1], af[kk + 1]);
        }
        asm volatile("s_nop 7\n\ts_nop 7");  // MFMA D -> VALU hazard guard
      }
      const int slot = t & (RD - 1);
      while (__hip_atomic_load(&wrote_s, __ATOMIC_ACQUIRE,
                               __HIP_MEMORY_SCOPE_WORKGROUP) < t + 1) {}
      float fr[4], fz[4], fn[4], fx[4];
#pragma unroll
      for (int jj = 0; jj < 4; ++jj) {
        fr[jj] = fifo[slot][lane][jj];
        fz[jj] = fifo[slot][lane][4 + jj];
        fn[jj] = fifo[slot][lane][8 + jj];
        fx[jj] = fifo[slot][lane][12 + jj];
      }
      __hip_atomic_store(&consumed_s, t + 1, __ATOMIC_RELEASE,
                         __HIP_MEMORY_SCOPE_WORKGROUP);

      unsigned short us[4]; f32x4 h2v;
#pragma unroll
      for (int jj = 0; jj < 4; ++jj) {
        const float ghr = a0[jj] + a1[jj] + bh0[jj];
        const float ghz = a2[jj] + a3[jj] + bh1[jj];
        const float ghn = a4[jj] + a5[jj] + bh2[jj];
        const float rr = 1.f / (1.f + __expf(-(fr[jj] + ghr)));
        const float zz = 1.f / (1.f + __expf(-(fz[jj] + ghz)));
        const float ee = __expf(2.f * (fn[jj] + rr * ghn));
        const float nn = 1.f - 2.f / (ee + 1.f);        // tanh, inf-safe
        const float h2 = (1.f - zz) * nn + zz * hc[jj] + fx[jj];
        hc[jj] = h2; h2v[jj] = h2; us[jj] = f2bf(h2);
      }
      // --- h publish: lane holds 4 ADJACENT cols -> 2 dwords in-lane,
      //     one shfl_xor(16) merges partner's 8B -> 16B store per even-hi lane.
      const unsigned int dw0 = (unsigned int)us[0] | ((unsigned int)us[1] << 16);
      const unsigned int dw1 = (unsigned int)us[2] | ((unsigned int)us[3] << 16);
      const unsigned int p0 = (unsigned int)__shfl_xor((int)dw0, 16);
      const unsigned int p1 = (unsigned int)__shfl_xor((int)dw1, 16);
      if (!(hi & 1)) {
        int4v pk; pk[0] = (int)dw0; pk[1] = (int)dw1;
        pk[2] = (int)p0; pk[3] = (int)p1;
        unsigned short* wp =
            Hst + (size_t)(t * BB + l15) * FF + j * 16 + (hi >> 1) * 8;
        asm volatile("global_store_dwordx4 %0, %1, off sc0 sc1"
                     :: "v"(wp), "v"(pk) : "memory");
      }
      asm volatile("s_waitcnt vmcnt(0)" ::: "memory");   // h at coherence point
      if (lane == 0) {                 // publish to all 4 replica lines
#pragma unroll
        for (int r = 0; r < 4; ++r)
          __hip_atomic_store(flg + r * 32 + j, t + 1, __ATOMIC_RELAXED,
                             __HIP_MEMORY_SCOPE_AGENT);
      }
      // out store (off critical path, after flag): one dwordx4 per lane
      if (t >= LL && t < TT - LL) {
        float* op = out + ((size_t)l15 * (TT - 2 * LL) + (t - LL)) * 1024
                  + d * 512 + cb;
        *(f32x4*)op = h2v;
      }
    }
  } else {
    // ====================== WAVE B: gi + residual -> FIFO ==================
    const f32x4 bi0 = *(const f32x4*)(bih + cb);
    const f32x4 bi1 = *(const f32x4*)(bih + 512 + cb);
    const f32x4 bi2 = *(const f32x4*)(bih + 1024 + cb);
    for (int t = 0; t < TT; ++t) {
      const int slot = t & (RD - 1);
      while (t - __hip_atomic_load(&consumed_s, __ATOMIC_ACQUIRE,
                                   __HIP_MEMORY_SCOPE_WORKGROUP) >= RD) {}
      const int tx = d ? (TT - 1 - t) : t;
      const unsigned short* Arow = Xb + (size_t)(tx * BB + l15) * FF + lk;
      int4v af[16];
#pragma unroll
      for (int kk = 0; kk < 16; ++kk)
        af[kk] = *(const int4v*)(Arow + kk * 32);
      f32x4 a0 = {0,0,0,0}, a1 = {0,0,0,0}, a2 = {0,0,0,0},
            a3 = {0,0,0,0}, a4 = {0,0,0,0}, a5 = {0,0,0,0};
#pragma unroll
      for (int kk = 0; kk < 16; kk += 2) {
        MFMA_WA(a0, wf[0][kk],     af[kk]);
        MFMA_WA(a2, wf[1][kk],     af[kk]);
        MFMA_WA(a4, wf[2][kk],     af[kk]);
        MFMA_WA(a1, wf[0][kk + 1], af[kk + 1]);
        MFMA_WA(a3, wf[1][kk + 1], af[kk + 1]);
        MFMA_WA(a5, wf[2][kk + 1], af[kk + 1]);
      }
      asm volatile("s_nop 7\n\ts_nop 7");
      // residual x: 4 adjacent bf16 = one 8B load
      const int2v xw = *(const int2v*)(Xb + (size_t)(tx * BB + l15) * FF + cb);
      float xv[4];
      xv[0] = bf2f((unsigned short)(xw[0] & 0xffff));
      xv[1] = bf2f((unsigned short)((unsigned int)xw[0] >> 16));
      xv[2] = bf2f((unsigned short)(xw[1] & 0xffff));
      xv[3] = bf2f((unsigned short)((unsigned int)xw[1] >> 16));
#pragma unroll
      for (int jj = 0; jj < 4; ++jj) {
        fifo[slot][lane][jj]      = a0[jj] + a1[jj] + bi0[jj];
        fifo[slot][lane][4 + jj]  = a2[jj] + a3[jj] + bi1[jj];
        fifo[slot][lane][8 + jj]  = a4[jj] + a5[jj] + bi2[jj];
        fifo[slot][lane][12 + jj] = xv[jj];
      }
      __hip_atomic_store(&wrote_s, t + 1, __ATOMIC_RELEASE,
                         __HIP_MEMORY_SCOPE_WORKGROUP);
    }
  }
}

// ---------------------------------------------------------------------------
extern "C" void kernel_launch(void* const* d_in, const int* in_sizes, int n_in,
                              void* d_out, int out_size, void* d_ws, size_t ws_size,
                              hipStream_t stream) {
  const float* x     = (const float*)d_in[0];
  const float* Wih_f = (const float*)d_in[1];
  const float* Whh_f = (const float*)d_in[2];
  const float* bih_f = (const float*)d_in[3];
  const float* bhh_f = (const float*)d_in[4];
  const float* Wih_b = (const float*)d_in[5];
  const float* Whh_b = (const float*)d_in[6];
  const float* bih_b = (const float*)d_in[7];
  const float* bhh_b = (const float*)d_in[8];
  float* out = (float*)d_out;

  char* ws = (char*)d_ws;
  unsigned short* Xb = (unsigned short*)ws;
  unsigned short* Hf = (unsigned short*)(ws + (size_t)33554432);
  unsigned short* Hb = (unsigned short*)(ws + (size_t)2 * 33554432);
  unsigned short* Wb = (unsigned short*)(ws + (size_t)3 * 33554432);
  int* flags         = (int*)(ws + (size_t)3 * 33554432 + 6291456);

  prep_x<<<65536, 256, 0, stream>>>(x, Xb);
  prep_w<<<12288, 256, 0, stream>>>(Whh_f, Wih_f, Whh_b, Wih_b, Wb);
  prep_flags<<<1, 256, 0, stream>>>(flags);
  bigru_rec<<<64, NTHR, 0, stream>>>(Xb, Hf, Hb, Wb, bih_f, bhh_f, bih_b, bhh_b,
                                     flags, out);
}